// Round 2
// baseline (865.018 us; speedup 1.0000x reference)
//
#include <hip/hip_runtime.h>

#define Hdim 1024
#define Fdim 4096
#define NE   8
#define NT   2048
#define MT_MAX 16   // worst case: one expert takes all 2048 tokens / 128 rows per tile
#define KSPLIT 4    // k_down K-dim split for occupancy

typedef __attribute__((ext_vector_type(8))) short short8;
typedef __attribute__((ext_vector_type(4))) short short4v;
typedef __attribute__((ext_vector_type(4))) float f32x4;

// fp32 -> bf16 round-to-nearest-even
__device__ __forceinline__ unsigned short bf16r(float f) {
  union { float fv; unsigned u; } v; v.fv = f;
  unsigned u = v.u;
  return (unsigned short)((u + 0x7FFFu + ((u >> 16) & 1u)) >> 16);
}

// ---------------- K1: router (4 waves/block, one token per wave) ----------------
__global__ void k_router(const float* __restrict__ x, const float* __restrict__ gw,
                         int* __restrict__ counts, int* __restrict__ sel,
                         float* __restrict__ selw) {
  int wave = threadIdx.x >> 6;
  int l    = threadIdx.x & 63;
  int t    = blockIdx.x * 4 + wave;
  const float* xp = x + (size_t)t * Hdim;
  float acc[NE];
#pragma unroll
  for (int e = 0; e < NE; e++) acc[e] = 0.f;
  for (int h = l; h < Hdim; h += 64) {
    float xv = xp[h];
#pragma unroll
    for (int e = 0; e < NE; e++) acc[e] += xv * gw[e * Hdim + h];
  }
#pragma unroll
  for (int e = 0; e < NE; e++) {
    float v = acc[e];
#pragma unroll
    for (int off = 32; off > 0; off >>= 1) v += __shfl_down(v, off, 64);
    acc[e] = v;
  }
  if (l == 0) {
    int b0 = 0; float v0 = acc[0];
    for (int e = 1; e < NE; e++) if (acc[e] > v0) { v0 = acc[e]; b0 = e; }
    int b1 = -1; float v1 = -1e30f;
    for (int e = 0; e < NE; e++) if (e != b0 && acc[e] > v1) { v1 = acc[e]; b1 = e; }
    // normalized top-2 softmax weights: w0 = p0/(p0+p1) = 1/(1+exp(l1-l0))
    float w0 = 1.f / (1.f + expf(v1 - v0));
    atomicAdd(&counts[b0], 1);
    atomicAdd(&counts[b1], 1);
    sel[2 * t]     = b0;
    sel[2 * t + 1] = b1;
    selw[2 * t]     = w0;
    selw[2 * t + 1] = 1.f - w0;
  }
}

// ---------------- K2: fused scan + scatter (single block) ----------------
__global__ void k_scatter(const int* __restrict__ counts, const int* __restrict__ sel,
                          const float* __restrict__ selw, int* __restrict__ offsets,
                          int* __restrict__ rowids, float* __restrict__ pairw) {
  __shared__ int soff[NE];
  __shared__ int scur[NE];
  if (threadIdx.x == 0) {
    int s = 0;
    for (int e = 0; e < NE; e++) { soff[e] = s; offsets[e] = s; s += counts[e]; scur[e] = 0; }
  }
  __syncthreads();
  for (int t = threadIdx.x; t < NT; t += blockDim.x) {
#pragma unroll
    for (int j = 0; j < 2; j++) {
      int e = sel[2 * t + j];
      int p = atomicAdd(&scur[e], 1);
      rowids[soff[e] + p] = t;
      pairw[soff[e] + p]  = selw[2 * t + j];
    }
  }
}

// ---------------- K3: gate_up GEMM + gelu, fused ----------------
// block tile: 128 pair-rows x 64 f-cols (gate at f, up at F+f staged as Bs rows 64..127).
// Each wave owns 64 rows (wy) x 32 f-cols (wx) and computes BOTH gate and up for
// those cols -> hact = up * gelu(gate) entirely in-register, no cross-wave LDS.
__global__ __launch_bounds__(256, 2)
void k_gate_up(const float* __restrict__ x, const float* __restrict__ gup,
               const int* __restrict__ counts, const int* __restrict__ offsets,
               const int* __restrict__ rowids, unsigned short* __restrict__ hact) {
  int e  = blockIdx.y >> 4;
  int mt = blockIdx.y & 15;
  int n  = counts[e];
  if (mt * 128 >= n) return;
  int base = offsets[e];
  int row0 = mt * 128;
  int f0   = blockIdx.x * 64;

  __shared__ __align__(16) unsigned short As[128][32];
  __shared__ __align__(16) unsigned short Bs[128][32];
  __shared__ int rid[128];

  int tid = threadIdx.x;
  if (tid < 128) {
    int r = row0 + tid;
    rid[tid] = (r < n) ? rowids[base + r] : rowids[base];
  }
  __syncthreads();

  int kc   = (tid & 7) * 4;   // k offset (floats) within 32
  int trow = tid >> 3;        // 0..31
  const float* ap[4];
  const float* bp[4];
#pragma unroll
  for (int p = 0; p < 4; p++) {
    int ar = p * 32 + trow;
    ap[p] = x + (size_t)rid[ar] * Hdim + kc;
    int f = (ar < 64) ? (f0 + ar) : (Fdim + f0 + (ar - 64));
    bp[p] = gup + ((size_t)e * 2 * Fdim + f) * Hdim + kc;
  }

  int wave = tid >> 6, lane = tid & 63;
  int wy = wave >> 1, wx = wave & 1;
  int lrow = lane & 15, lk = (lane >> 4) * 8;
  f32x4 acc[4][4] = {};   // [i: row frag][j: 0,1=gate cols, 2,3=up cols]

  for (int k0 = 0; k0 < Hdim; k0 += 32) {
    __syncthreads();
#pragma unroll
    for (int p = 0; p < 4; p++) {
      int ar = p * 32 + trow;
      float4 av = *(const float4*)(ap[p] + k0);
      short4v sa;
      sa.x = (short)bf16r(av.x); sa.y = (short)bf16r(av.y);
      sa.z = (short)bf16r(av.z); sa.w = (short)bf16r(av.w);
      *(short4v*)&As[ar][kc] = sa;
      float4 bv = *(const float4*)(bp[p] + k0);
      short4v sb;
      sb.x = (short)bf16r(bv.x); sb.y = (short)bf16r(bv.y);
      sb.z = (short)bf16r(bv.z); sb.w = (short)bf16r(bv.w);
      *(short4v*)&Bs[ar][kc] = sb;
    }
    __syncthreads();
    short8 a[4], b[4];
#pragma unroll
    for (int i = 0; i < 4; i++) a[i] = *(const short8*)&As[wy * 64 + i * 16 + lrow][lk];
    b[0] = *(const short8*)&Bs[wx * 32 + lrow][lk];
    b[1] = *(const short8*)&Bs[wx * 32 + 16 + lrow][lk];
    b[2] = *(const short8*)&Bs[64 + wx * 32 + lrow][lk];
    b[3] = *(const short8*)&Bs[64 + wx * 32 + 16 + lrow][lk];
#pragma unroll
    for (int i = 0; i < 4; i++)
#pragma unroll
      for (int j = 0; j < 4; j++)
        acc[i][j] = __builtin_amdgcn_mfma_f32_16x16x32_bf16(a[i], b[j], acc[i][j], 0, 0, 0);
  }

  int quad = lane >> 4;
#pragma unroll
  for (int i = 0; i < 4; i++) {
#pragma unroll
    for (int r = 0; r < 4; r++) {
      int rl = row0 + wy * 64 + i * 16 + quad * 4 + r;
      if (rl < n) {
        size_t rowoff = (size_t)(base + rl) * Fdim + f0 + wx * 32;
#pragma unroll
        for (int j = 0; j < 2; j++) {
          float g = acc[i][j][r];
          float u = acc[i][j + 2][r];
          float ge = 0.5f * g * (1.f + erff(g * 0.70710678118654752f));
          hact[rowoff + j * 16 + lrow] = bf16r(u * ge);
        }
      }
    }
  }
}

// ---------------- K4: down GEMM + weighted scatter-add (K-split) ----------------
__global__ __launch_bounds__(256, 2)
void k_down(const unsigned short* __restrict__ hact, const float* __restrict__ dw,
            const int* __restrict__ counts, const int* __restrict__ offsets,
            const int* __restrict__ rowids, const float* __restrict__ pairw,
            float* __restrict__ out) {
  int e  = blockIdx.y >> 4;
  int mt = blockIdx.y & 15;
  int n  = counts[e];
  if (mt * 128 >= n) return;
  int base = offsets[e];
  int row0 = mt * 128;
  int h0   = blockIdx.x * 128;
  int kbeg = blockIdx.z * (Fdim / KSPLIT);
  int kend = kbeg + Fdim / KSPLIT;

  __shared__ __align__(16) unsigned short As[128][32];
  __shared__ __align__(16) unsigned short Bs[128][32];

  int tid = threadIdx.x;
  int wave = tid >> 6, lane = tid & 63;
  int wy = wave >> 1, wx = wave & 1;
  int lrow = lane & 15, lk = (lane >> 4) * 8;

  const unsigned short* asrc[2];
#pragma unroll
  for (int p = 0; p < 2; p++) {
    int idx = p * 256 + tid;
    int row = idx >> 2, seg = idx & 3;
    int slot = base + row0 + row;
    if (slot > NT * 2 - 1) slot = NT * 2 - 1;  // tail rows: clamp (discarded later)
    asrc[p] = hact + (size_t)slot * Fdim + seg * 8;
  }
  int kc   = (tid & 7) * 4;
  int trow = tid >> 3;
  const float* bp[4];
#pragma unroll
  for (int p = 0; p < 4; p++) {
    int j = p * 32 + trow;
    bp[p] = dw + ((size_t)e * Hdim + h0 + j) * Fdim + kc;
  }

  f32x4 acc[4][4] = {};
  for (int k0 = kbeg; k0 < kend; k0 += 32) {
    __syncthreads();
#pragma unroll
    for (int p = 0; p < 2; p++) {
      int idx = p * 256 + tid;
      int row = idx >> 2, seg = idx & 3;
      *(int4*)&As[row][seg * 8] = *(const int4*)(asrc[p] + k0);
    }
#pragma unroll
    for (int p = 0; p < 4; p++) {
      int j = p * 32 + trow;
      float4 bv = *(const float4*)(bp[p] + k0);
      short4v sb;
      sb.x = (short)bf16r(bv.x); sb.y = (short)bf16r(bv.y);
      sb.z = (short)bf16r(bv.z); sb.w = (short)bf16r(bv.w);
      *(short4v*)&Bs[j][kc] = sb;
    }
    __syncthreads();
    short8 a[4], b[4];
#pragma unroll
    for (int i = 0; i < 4; i++) a[i] = *(const short8*)&As[wy * 64 + i * 16 + lrow][lk];
#pragma unroll
    for (int j = 0; j < 4; j++) b[j] = *(const short8*)&Bs[wx * 64 + j * 16 + lrow][lk];
#pragma unroll
    for (int i = 0; i < 4; i++)
#pragma unroll
      for (int j = 0; j < 4; j++)
        acc[i][j] = __builtin_amdgcn_mfma_f32_16x16x32_bf16(a[i], b[j], acc[i][j], 0, 0, 0);
  }

  int quad = lane >> 4;
#pragma unroll
  for (int i = 0; i < 4; i++) {
#pragma unroll
    for (int r = 0; r < 4; r++) {
      int rl = row0 + wy * 64 + i * 16 + quad * 4 + r;
      if (rl < n) {
        int slot = base + rl;
        int t    = rowids[slot];
        float wv = pairw[slot];
        float* op = out + (size_t)t * Hdim + h0 + wx * 64;
#pragma unroll
        for (int j = 0; j < 4; j++)
          atomicAdd(op + j * 16 + lrow, wv * acc[i][j][r]);
      }
    }
  }
}

extern "C" void kernel_launch(void* const* d_in, const int* in_sizes, int n_in,
                              void* d_out, int out_size, void* d_ws, size_t ws_size,
                              hipStream_t stream) {
  const float* x   = (const float*)d_in[0];   // (1, 2048, 1024)
  const float* gw  = (const float*)d_in[1];   // (8, 1024)
  const float* gup = (const float*)d_in[2];   // (8, 8192, 1024)
  const float* dwn = (const float*)d_in[3];   // (8, 1024, 4096)
  float* out = (float*)d_out;                 // (1, 2048, 1024) fp32

  char* ws = (char*)d_ws;
  int*   counts  = (int*)(ws + 0);
  int*   offsets = (int*)(ws + 128);
  int*   sel     = (int*)(ws + 4096);                  // 2048*2 ints
  float* selw    = (float*)(ws + 4096 + 16384);        // 2048*2 floats
  int*   rowids  = (int*)(ws + 4096 + 32768);          // 4096 ints
  float* pairw   = (float*)(ws + 4096 + 49152);        // 4096 floats
  unsigned short* hact = (unsigned short*)(ws + (1 << 20));  // 4096 x 4096 bf16 = 32 MB

  hipMemsetAsync(ws, 0, 4096, stream);                         // counts
  hipMemsetAsync(d_out, 0, (size_t)out_size * sizeof(float), stream);

  k_router<<<NT / 4, 256, 0, stream>>>(x, gw, counts, sel, selw);
  k_scatter<<<1, 1024, 0, stream>>>(counts, sel, selw, offsets, rowids, pairw);
  k_gate_up<<<dim3(Fdim / 64, NE * MT_MAX), 256, 0, stream>>>(x, gup, counts, offsets, rowids, hact);
  k_down<<<dim3(Hdim / 128, NE * MT_MAX, KSPLIT), 256, 0, stream>>>(hact, dwn, counts, offsets, rowids, pairw, out);
}

// Round 3
// 780.612 us; speedup vs baseline: 1.1081x; 1.1081x over previous
//
#include <hip/hip_runtime.h>

#define Hdim 1024
#define Fdim 4096
#define NE   8
#define NT   2048
#define MT_MAX 16   // worst case: one expert takes all 2048 tokens / 128 rows per tile
#define KSPLIT 4    // k_down K-dim split for occupancy

typedef __attribute__((ext_vector_type(8))) short short8;
typedef __attribute__((ext_vector_type(4))) short short4v;
typedef __attribute__((ext_vector_type(4))) float f32x4;

// fp32 -> bf16 round-to-nearest-even
__device__ __forceinline__ unsigned short bf16r(float f) {
  union { float fv; unsigned u; } v; v.fv = f;
  unsigned u = v.u;
  return (unsigned short)((u + 0x7FFFu + ((u >> 16) & 1u)) >> 16);
}

// ---------------- K1: router (4 waves/block, one token per wave) ----------------
__global__ void k_router(const float* __restrict__ x, const float* __restrict__ gw,
                         int* __restrict__ counts, int* __restrict__ sel,
                         float* __restrict__ selw) {
  int wave = threadIdx.x >> 6;
  int l    = threadIdx.x & 63;
  int t    = blockIdx.x * 4 + wave;
  const float* xp = x + (size_t)t * Hdim;
  float acc[NE];
#pragma unroll
  for (int e = 0; e < NE; e++) acc[e] = 0.f;
  for (int h = l; h < Hdim; h += 64) {
    float xv = xp[h];
#pragma unroll
    for (int e = 0; e < NE; e++) acc[e] += xv * gw[e * Hdim + h];
  }
#pragma unroll
  for (int e = 0; e < NE; e++) {
    float v = acc[e];
#pragma unroll
    for (int off = 32; off > 0; off >>= 1) v += __shfl_down(v, off, 64);
    acc[e] = v;
  }
  if (l == 0) {
    int b0 = 0; float v0 = acc[0];
    for (int e = 1; e < NE; e++) if (acc[e] > v0) { v0 = acc[e]; b0 = e; }
    int b1 = -1; float v1 = -1e30f;
    for (int e = 0; e < NE; e++) if (e != b0 && acc[e] > v1) { v1 = acc[e]; b1 = e; }
    // normalized top-2 softmax weights: w0 = p0/(p0+p1) = 1/(1+exp(l1-l0))
    float w0 = 1.f / (1.f + expf(v1 - v0));
    atomicAdd(&counts[b0], 1);
    atomicAdd(&counts[b1], 1);
    sel[2 * t]     = b0;
    sel[2 * t + 1] = b1;
    selw[2 * t]     = w0;
    selw[2 * t + 1] = 1.f - w0;
  }
}

// ---------------- K2: fused scan + scatter (single block) ----------------
__global__ void k_scatter(const int* __restrict__ counts, const int* __restrict__ sel,
                          const float* __restrict__ selw, int* __restrict__ offsets,
                          int* __restrict__ rowids, float* __restrict__ pairw) {
  __shared__ int soff[NE];
  __shared__ int scur[NE];
  if (threadIdx.x == 0) {
    int s = 0;
    for (int e = 0; e < NE; e++) { soff[e] = s; offsets[e] = s; s += counts[e]; scur[e] = 0; }
  }
  __syncthreads();
  for (int t = threadIdx.x; t < NT; t += blockDim.x) {
#pragma unroll
    for (int j = 0; j < 2; j++) {
      int e = sel[2 * t + j];
      int p = atomicAdd(&scur[e], 1);
      rowids[soff[e] + p] = t;
      pairw[soff[e] + p]  = selw[2 * t + j];
    }
  }
}

// ---------------- K3: gate_up GEMM + gelu, fused, 1-deep register prefetch ----------------
// block tile: 128 pair-rows x 64 f-cols (gate at f, up at F+f staged as Bs rows 64..127).
// Each wave owns 64 rows (wy) x 32 f-cols (wx), computes BOTH gate and up in-register.
__global__ __launch_bounds__(256, 2)
void k_gate_up(const float* __restrict__ x, const float* __restrict__ gup,
               const int* __restrict__ counts, const int* __restrict__ offsets,
               const int* __restrict__ rowids, unsigned short* __restrict__ hact) {
  int e  = blockIdx.y >> 4;
  int mt = blockIdx.y & 15;
  int n  = counts[e];
  if (mt * 128 >= n) return;
  int base = offsets[e];
  int row0 = mt * 128;
  int f0   = blockIdx.x * 64;

  __shared__ __align__(16) unsigned short As[128][32];
  __shared__ __align__(16) unsigned short Bs[128][32];
  __shared__ int rid[128];

  int tid = threadIdx.x;
  if (tid < 128) {
    int r = row0 + tid;
    rid[tid] = (r < n) ? rowids[base + r] : rowids[base];
  }
  __syncthreads();

  int kc   = (tid & 7) * 4;   // k offset (floats) within 32
  int trow = tid >> 3;        // 0..31
  const float* ap[4];
  const float* bp[4];
#pragma unroll
  for (int p = 0; p < 4; p++) {
    int ar = p * 32 + trow;
    ap[p] = x + (size_t)rid[ar] * Hdim + kc;
    int f = (ar < 64) ? (f0 + ar) : (Fdim + f0 + (ar - 64));
    bp[p] = gup + ((size_t)e * 2 * Fdim + f) * Hdim + kc;
  }

  int wave = tid >> 6, lane = tid & 63;
  int wy = wave >> 1, wx = wave & 1;
  int lrow = lane & 15, lk = (lane >> 4) * 8;
  f32x4 acc[4][4] = {};   // [i: row frag][j: 0,1=gate cols, 2,3=up cols]

  // preload k=0
  float4 ra[4], rb[4];
#pragma unroll
  for (int p = 0; p < 4; p++) { ra[p] = *(const float4*)(ap[p]); rb[p] = *(const float4*)(bp[p]); }

  for (int k0 = 0; k0 < Hdim; k0 += 32) {
    __syncthreads();
#pragma unroll
    for (int p = 0; p < 4; p++) {
      int ar = p * 32 + trow;
      short4v sa;
      sa.x = (short)bf16r(ra[p].x); sa.y = (short)bf16r(ra[p].y);
      sa.z = (short)bf16r(ra[p].z); sa.w = (short)bf16r(ra[p].w);
      *(short4v*)&As[ar][kc] = sa;
      short4v sb;
      sb.x = (short)bf16r(rb[p].x); sb.y = (short)bf16r(rb[p].y);
      sb.z = (short)bf16r(rb[p].z); sb.w = (short)bf16r(rb[p].w);
      *(short4v*)&Bs[ar][kc] = sb;
    }
    // issue next tile's loads; they fly across the MFMA phase + barrier
    if (k0 + 32 < Hdim) {
#pragma unroll
      for (int p = 0; p < 4; p++) {
        ra[p] = *(const float4*)(ap[p] + k0 + 32);
        rb[p] = *(const float4*)(bp[p] + k0 + 32);
      }
    }
    __syncthreads();
    short8 a[4], b[4];
#pragma unroll
    for (int i = 0; i < 4; i++) a[i] = *(const short8*)&As[wy * 64 + i * 16 + lrow][lk];
    b[0] = *(const short8*)&Bs[wx * 32 + lrow][lk];
    b[1] = *(const short8*)&Bs[wx * 32 + 16 + lrow][lk];
    b[2] = *(const short8*)&Bs[64 + wx * 32 + lrow][lk];
    b[3] = *(const short8*)&Bs[64 + wx * 32 + 16 + lrow][lk];
#pragma unroll
    for (int i = 0; i < 4; i++)
#pragma unroll
      for (int j = 0; j < 4; j++)
        acc[i][j] = __builtin_amdgcn_mfma_f32_16x16x32_bf16(a[i], b[j], acc[i][j], 0, 0, 0);
  }

  int quad = lane >> 4;
#pragma unroll
  for (int i = 0; i < 4; i++) {
#pragma unroll
    for (int r = 0; r < 4; r++) {
      int rl = row0 + wy * 64 + i * 16 + quad * 4 + r;
      if (rl < n) {
        size_t rowoff = (size_t)(base + rl) * Fdim + f0 + wx * 32;
#pragma unroll
        for (int j = 0; j < 2; j++) {
          float g = acc[i][j][r];
          float u = acc[i][j + 2][r];
          float ge = 0.5f * g * (1.f + erff(g * 0.70710678118654752f));
          hact[rowoff + j * 16 + lrow] = bf16r(u * ge);
        }
      }
    }
  }
}

// ---------------- K4: down GEMM + weighted scatter-add (K-split, prefetch) ----------------
__global__ __launch_bounds__(256, 2)
void k_down(const unsigned short* __restrict__ hact, const float* __restrict__ dw,
            const int* __restrict__ counts, const int* __restrict__ offsets,
            const int* __restrict__ rowids, const float* __restrict__ pairw,
            float* __restrict__ out) {
  int e  = blockIdx.y >> 4;
  int mt = blockIdx.y & 15;
  int n  = counts[e];
  if (mt * 128 >= n) return;
  int base = offsets[e];
  int row0 = mt * 128;
  int h0   = blockIdx.x * 128;
  int kbeg = blockIdx.z * (Fdim / KSPLIT);
  int kend = kbeg + Fdim / KSPLIT;

  __shared__ __align__(16) unsigned short As[128][32];
  __shared__ __align__(16) unsigned short Bs[128][32];

  int tid = threadIdx.x;
  int wave = tid >> 6, lane = tid & 63;
  int wy = wave >> 1, wx = wave & 1;
  int lrow = lane & 15, lk = (lane >> 4) * 8;

  const unsigned short* asrc[2];
#pragma unroll
  for (int p = 0; p < 2; p++) {
    int idx = p * 256 + tid;
    int row = idx >> 2, seg = idx & 3;
    int slot = base + row0 + row;
    if (slot > NT * 2 - 1) slot = NT * 2 - 1;  // tail rows: clamp (discarded later)
    asrc[p] = hact + (size_t)slot * Fdim + seg * 8;
  }
  int kc   = (tid & 7) * 4;
  int trow = tid >> 3;
  const float* bp[4];
#pragma unroll
  for (int p = 0; p < 4; p++) {
    int j = p * 32 + trow;
    bp[p] = dw + ((size_t)e * Hdim + h0 + j) * Fdim + kc;
  }

  // preload first k-chunk
  int4   raw[2];
  float4 rbw[4];
#pragma unroll
  for (int p = 0; p < 2; p++) raw[p] = *(const int4*)(asrc[p] + kbeg);
#pragma unroll
  for (int p = 0; p < 4; p++) rbw[p] = *(const float4*)(bp[p] + kbeg);

  f32x4 acc[4][4] = {};
  for (int k0 = kbeg; k0 < kend; k0 += 32) {
    __syncthreads();
#pragma unroll
    for (int p = 0; p < 2; p++) {
      int idx = p * 256 + tid;
      int row = idx >> 2, seg = idx & 3;
      *(int4*)&As[row][seg * 8] = raw[p];
    }
#pragma unroll
    for (int p = 0; p < 4; p++) {
      int j = p * 32 + trow;
      short4v sb;
      sb.x = (short)bf16r(rbw[p].x); sb.y = (short)bf16r(rbw[p].y);
      sb.z = (short)bf16r(rbw[p].z); sb.w = (short)bf16r(rbw[p].w);
      *(short4v*)&Bs[j][kc] = sb;
    }
    if (k0 + 32 < kend) {
#pragma unroll
      for (int p = 0; p < 2; p++) raw[p] = *(const int4*)(asrc[p] + k0 + 32);
#pragma unroll
      for (int p = 0; p < 4; p++) rbw[p] = *(const float4*)(bp[p] + k0 + 32);
    }
    __syncthreads();
    short8 a[4], b[4];
#pragma unroll
    for (int i = 0; i < 4; i++) a[i] = *(const short8*)&As[wy * 64 + i * 16 + lrow][lk];
#pragma unroll
    for (int j = 0; j < 4; j++) b[j] = *(const short8*)&Bs[wx * 64 + j * 16 + lrow][lk];
#pragma unroll
    for (int i = 0; i < 4; i++)
#pragma unroll
      for (int j = 0; j < 4; j++)
        acc[i][j] = __builtin_amdgcn_mfma_f32_16x16x32_bf16(a[i], b[j], acc[i][j], 0, 0, 0);
  }

  int quad = lane >> 4;
#pragma unroll
  for (int i = 0; i < 4; i++) {
#pragma unroll
    for (int r = 0; r < 4; r++) {
      int rl = row0 + wy * 64 + i * 16 + quad * 4 + r;
      if (rl < n) {
        int slot = base + rl;
        int t    = rowids[slot];
        float wv = pairw[slot];
        float* op = out + (size_t)t * Hdim + h0 + wx * 64;
#pragma unroll
        for (int j = 0; j < 4; j++)
          atomicAdd(op + j * 16 + lrow, wv * acc[i][j][r]);
      }
    }
  }
}

extern "C" void kernel_launch(void* const* d_in, const int* in_sizes, int n_in,
                              void* d_out, int out_size, void* d_ws, size_t ws_size,
                              hipStream_t stream) {
  const float* x   = (const float*)d_in[0];   // (1, 2048, 1024)
  const float* gw  = (const float*)d_in[1];   // (8, 1024)
  const float* gup = (const float*)d_in[2];   // (8, 8192, 1024)
  const float* dwn = (const float*)d_in[3];   // (8, 1024, 4096)
  float* out = (float*)d_out;                 // (1, 2048, 1024) fp32

  char* ws = (char*)d_ws;
  int*   counts  = (int*)(ws + 0);
  int*   offsets = (int*)(ws + 128);
  int*   sel     = (int*)(ws + 4096);                  // 2048*2 ints
  float* selw    = (float*)(ws + 4096 + 16384);        // 2048*2 floats
  int*   rowids  = (int*)(ws + 4096 + 32768);          // 4096 ints
  float* pairw   = (float*)(ws + 4096 + 49152);        // 4096 floats
  unsigned short* hact = (unsigned short*)(ws + (1 << 20));  // 4096 x 4096 bf16 = 32 MB

  hipMemsetAsync(ws, 0, 4096, stream);                         // counts
  hipMemsetAsync(d_out, 0, (size_t)out_size * sizeof(float), stream);

  k_router<<<NT / 4, 256, 0, stream>>>(x, gw, counts, sel, selw);
  k_scatter<<<1, 1024, 0, stream>>>(counts, sel, selw, offsets, rowids, pairw);
  k_gate_up<<<dim3(Fdim / 64, NE * MT_MAX), 256, 0, stream>>>(x, gup, counts, offsets, rowids, hact);
  k_down<<<dim3(Hdim / 128, NE * MT_MAX, KSPLIT), 256, 0, stream>>>(hact, dwn, counts, offsets, rowids, pairw, out);
}